// Round 15
// baseline (5974.613 us; speedup 1.0000x reference)
//
#include <hip/hip_runtime.h>

// ---------------------------------------------------------------------------
// Fused recurrent multimodal net. T=128, N=2048. 128 blocks x 16 rows.
// Round 14: chunked waits. r13 falsified byte-BW model (pack L2-resident via
// nt-XP, FETCH halved, dur unchanged) => cost is per-s_waitcnt (~300cy each,
// m135). Ring now double-buffers 8-tile chunks: ONE vmcnt(8) per chunk
// (123 -> ~18 waits/step) and A-fragments are loaded inline per chunk so the
// compiler batches ds_reads (no serial ds_read->MFMA->ds_read chains).
// ---------------------------------------------------------------------------

#define T_STEPS 128

typedef __attribute__((ext_vector_type(8))) short bf16x8;
typedef __attribute__((ext_vector_type(4))) float f32x4;
typedef __attribute__((ext_vector_type(2))) unsigned long long ull2;

#define MFMA_B16(a,b,c) __builtin_amdgcn_mfma_f32_16x16x32_bf16((a),(b),(c),0,0,0)

__device__ __forceinline__ unsigned short f2b(float v) {
  union { float f; unsigned u; } x; x.f = v;
  unsigned r = x.u + 0x7fffu + ((x.u >> 16) & 1u);
  return (unsigned short)(r >> 16);
}
__device__ __forceinline__ float b2f(unsigned short u) {
  union { unsigned u; float f; } x; x.u = ((unsigned)u) << 16; return x.f;
}
__device__ __forceinline__ float sigm(float x){ return 1.0f/(1.0f + __expf(-x)); }
__device__ __forceinline__ float tanh_(float x){ return 1.0f - 2.0f/(1.0f + __expf(2.0f*x)); }

// ---- core LDS layout ----
#define OFF_XL     0
#define OFF_XA     10496
#define OFF_XI     13824
#define OFF_CSTAR  16128
#define OFF_ATT    30720
#define OFF_HID    45312
#define OFF_G1H    53760
#define OFF_G2H    56064
#define OFF_FEATS  58368
#define OFF_BIAS   69888
#define OFF_XP     79368
#define LDS_BYTES  110344   // >80KB: 1 block/CU

// ---- bias layout ----
#define BG_LIN 0
#define BG_AC  384
#define BG_IM  576
#define B_A1H  960
#define B_LOG  1088
#define B_A2H  1536
#define B_CHAT 1792
#define B_G1H  1920
#define B_G2H  1984
#define B_GM1  2048
#define B_GM2  2176
#define B_OUTH 2304
#define B_OUT2 2368
#define N_BIAS 2369

#define N_TILES 1718
#define PACK_BYTES ((size_t)N_TILES * 1024)
#define XP_ELEMS ((size_t)262144 * 960)
#define XP_BYTES (XP_ELEMS * 2)

#define LA(off,st,row,kk)  (*(const bf16x8*)(lds + (off) + ((((row)*(st)) + (kk)) << 1)))
#define LB(tile)           (*(const bf16x8*)(packc + (((size_t)(tile)) << 10) + (lane << 4)))
#define STB(off,st,row,col,v) (*(unsigned short*)(lds + (off) + ((((row)*(st)) + (col)) << 1)) = f2b(v))
#define LDB(off,st,row,col)   b2f(*(const unsigned short*)(lds + (off) + ((((row)*(st)) + (col)) << 1)))

struct PP { const float* p[35]; };

// ---------------------------------------------------------------------------
// Chunked register pipeline: 8-tile chunks, double-buffered, 1 vmcnt/chunk.
// ---------------------------------------------------------------------------
__device__ __forceinline__ void vmw(int n) {
  switch (n) {
    case 0:  asm volatile("s_waitcnt vmcnt(0)");  break;
    case 1:  asm volatile("s_waitcnt vmcnt(1)");  break;
    case 2:  asm volatile("s_waitcnt vmcnt(2)");  break;
    case 3:  asm volatile("s_waitcnt vmcnt(3)");  break;
    case 4:  asm volatile("s_waitcnt vmcnt(4)");  break;
    case 5:  asm volatile("s_waitcnt vmcnt(5)");  break;
    case 6:  asm volatile("s_waitcnt vmcnt(6)");  break;
    case 7:  asm volatile("s_waitcnt vmcnt(7)");  break;
    default: asm volatile("s_waitcnt vmcnt(8)");  break;
  }
  __builtin_amdgcn_sched_barrier(0);
}

#define ISSUE_B(dst, tile)                                                   \
  { unsigned off_ = (((unsigned)(tile)) << 10) + ((unsigned)lane << 4);      \
    asm volatile("global_load_dwordx4 %0, %1, %2"                            \
                 : "=v"(dst) : "v"(off_), "s"(packc)); }

// reg_loop: chunks of 8 tiles. Per chunk: issue next chunk's loads, ONE
// vmcnt(next_cnt) wait (current chunk resident), then 8 body calls (the
// compiler hoists/batches their LDS A-reads and uses fine lgkmcnt).
template<int NTT, class FT, class FB>
__device__ __forceinline__ void reg_loop(const char* packc, int lane,
                                         FT&& tile_of, FB&& body)
{
  constexpr int NC = (NTT + 7) >> 3;
  bf16x8 b[2][8];
  #pragma unroll
  for (int j = 0; j < 8; ++j) if (j < NTT) ISSUE_B(b[0][j], tile_of(j));
  #pragma unroll
  for (int c = 0; c < NC; ++c) {
    const int base = c * 8;
    const int cnt  = (NTT - base < 8) ? (NTT - base) : 8;
    const int nbase = base + 8;
    const int ncnt  = (NTT - nbase < 8) ? (NTT - nbase) : ((NTT - nbase < 0) ? 0 : 8);
    if (nbase < NTT) {
      #pragma unroll
      for (int j = 0; j < 8; ++j) if (j < ncnt) ISSUE_B(b[(c+1)&1][j], tile_of(nbase + j));
      vmw(ncnt);
    } else {
      vmw(0);
    }
    #pragma unroll
    for (int j = 0; j < 8; ++j) if (j < cnt) body(base + j, b[c&1][j]);
    __builtin_amdgcn_sched_barrier(0);
  }
}

// ---------------------------------------------------------------------------
// Pack kernel (r12/r13, unchanged)
// ---------------------------------------------------------------------------
__device__ __forceinline__ float gate_src(const float* Wih, const float* Whh,
                                          int H, int din, int nksx, int col, int k)
{
  int blk = col >> 6, gate = (col >> 4) & 3, u = col & 15;
  int unit = blk*16 + u;
  if (unit >= H) return 0.f;
  int row = gate*H + unit;
  int xk = nksx*32;
  if (k < xk) return (k < din) ? Wih[row*din + k] : 0.f;
  int kk = k - xk;
  return (kk < H) ? Whh[row*H + kk] : 0.f;
}
__device__ __forceinline__ float gate_h(const float* Whh, int H, int col, int k)
{
  int blk = col >> 6, gate = (col >> 4) & 3, u = col & 15;
  int unit = blk*16 + u;
  if (unit >= H || k >= H) return 0.f;
  return Whh[(gate*H + unit)*H + k];
}
__device__ __forceinline__ float gate_x(const float* Wih, int H, int din, int col, int k)
{
  int blk = col >> 6, gate = (col >> 4) & 3, u = col & 15;
  int unit = blk*16 + u;
  if (unit >= H || k >= din) return 0.f;
  return Wih[(gate*H + unit)*din + k];
}
__device__ __forceinline__ float plain_src(const float* W, int nout, int kdim, int col, int k)
{
  return (col < nout && k < kdim) ? W[col*kdim + k] : 0.f;
}

__global__ __launch_bounds__(256) void pack_kernel(PP P, unsigned short* __restrict__ pack,
                                                   float* __restrict__ bias)
{
  int tid = blockIdx.x*blockDim.x + threadIdx.x;
  int wv = tid >> 6, lane = tid & 63;
  int nw = (gridDim.x*blockDim.x) >> 6;
  int c = lane & 15, kg = lane >> 4;

  for (int tile = wv; tile < N_TILES; tile += nw) {
    unsigned short* dst = pack + ((size_t)tile << 9) + lane*8;
    #pragma unroll
    for (int i = 0; i < 8; ++i) {
      int r = tile; int nt, ks; float v; int kk;
      if (r < 312)       { nt=r/13; ks=r-nt*13; kk=ks*32+kg*8+i; v = gate_src(P.p[3], P.p[4], 88,300,10, nt*16+c, kk); }
      else if (r < 372)  { r-=312; nt=r/5;  ks=r-nt*5;  kk=ks*32+kg*8+i; v = gate_src(P.p[7], P.p[8], 48, 74, 3, nt*16+c, kk); }
      else if (r < 492)  { r-=372; nt=r/5;  ks=r-nt*5;  kk=ks*32+kg*8+i; v = gate_src(P.p[11],P.p[12],88, 35, 2, nt*16+c, kk); }
      else if (r < 604)  { r-=492; nt=r/14; ks=r-nt*14; kk=ks*32+kg*8+i; v = plain_src(P.p[15],128,448, nt*16+c, kk); }
      else if (r < 716)  { r-=604; nt=r/4;  ks=r-nt*4;  kk=ks*32+kg*8+i; v = plain_src(P.p[17],448,128, nt*16+c, kk); }
      else if (r < 940)  { r-=716; nt=r/14; ks=r-nt*14; kk=ks*32+kg*8+i; v = plain_src(P.p[19],256,448, nt*16+c, kk); }
      else if (r < 1004) { r-=940; nt=r/8;  ks=r-nt*8;  kk=ks*32+kg*8+i; v = plain_src(P.p[21],128,256, nt*16+c, kk); }
      else if (r < 1076) { r-=1004; nt=r/18; ks=r-nt*18; kk=ks*32+kg*8+i; v = plain_src(P.p[23], 64,576, nt*16+c, kk); }
      else if (r < 1148) { r-=1076; nt=r/18; ks=r-nt*18; kk=ks*32+kg*8+i; v = plain_src(P.p[27], 64,576, nt*16+c, kk); }
      else if (r < 1164) { r-=1148; nt=r/2;  ks=r-nt*2;  kk=ks*32+kg*8+i; v = plain_src(P.p[25],128, 64, nt*16+c, kk); }
      else if (r < 1180) { r-=1164; nt=r/2;  ks=r-nt*2;  kk=ks*32+kg*8+i; v = plain_src(P.p[29],128, 64, nt*16+c, kk); }
      else if (r < 1224) { r-=1180; nt=r/11; ks=r-nt*11; kk=ks*32+kg*8+i; v = plain_src(P.p[31], 64,352, nt*16+c, kk); }
      else if (r < 1226) { r-=1224; ks=r;    kk=ks*32+kg*8+i; v = plain_src(P.p[33],  1, 64, c, kk); }
      else if (r < 1298) { r-=1226; nt=r/3;  ks=r-nt*3;  kk=ks*32+kg*8+i; v = gate_h(P.p[4], 88, nt*16+c, kk); }
      else if (r < 1322) { r-=1298; nt=r/2;  ks=r-nt*2;  kk=ks*32+kg*8+i; v = gate_h(P.p[8], 48, nt*16+c, kk); }
      else if (r < 1394) { r-=1322; nt=r/3;  ks=r-nt*3;  kk=ks*32+kg*8+i; v = gate_h(P.p[12],88, nt*16+c, kk); }
      else if (r < 1634) { r-=1394; nt=r/10; ks=r-nt*10; kk=ks*32+kg*8+i; v = gate_x(P.p[3], 88,300, nt*16+c, kk); }
      else if (r < 1670) { r-=1634; nt=r/3;  ks=r-nt*3;  kk=ks*32+kg*8+i; v = gate_x(P.p[7], 48, 74, nt*16+c, kk); }
      else               { r-=1670; nt=r/2;  ks=r-nt*2;  kk=ks*32+kg*8+i; v = gate_x(P.p[11],88, 35, nt*16+c, kk); }
      dst[i] = f2b(v);
    }
  }

  int NT = gridDim.x*blockDim.x;
  for (int b = tid; b < N_BIAS; b += NT) {
    float v; int r = b;
    if (r < 384)       { int blk=r>>6, g=(r>>4)&3, u=r&15, un=blk*16+u; v = (un<88) ? P.p[5][g*88+un] + P.p[6][g*88+un]  : 0.f; }
    else if (r < 576)  { r-=384; int blk=r>>6, g=(r>>4)&3, u=r&15, un=blk*16+u; v = (un<48) ? P.p[9][g*48+un] + P.p[10][g*48+un] : 0.f; }
    else if (r < 960)  { r-=576; int blk=r>>6, g=(r>>4)&3, u=r&15, un=blk*16+u; v = (un<88) ? P.p[13][g*88+un]+ P.p[14][g*88+un] : 0.f; }
    else if (r < 1088) v = P.p[16][r-960];
    else if (r < 1536) v = P.p[18][r-1088];
    else if (r < 1792) v = P.p[20][r-1536];
    else if (r < 1920) v = P.p[22][r-1792];
    else if (r < 1984) v = P.p[24][r-1920];
    else if (r < 2048) v = P.p[28][r-1984];
    else if (r < 2176) v = P.p[26][r-2048];
    else if (r < 2304) v = P.p[30][r-2176];
    else if (r < 2368) v = P.p[32][r-2304];
    else               v = P.p[34][0];
    bias[b] = v;
  }
}

// ---------------------------------------------------------------------------
// XP pre-pass (r12, unchanged)
// ---------------------------------------------------------------------------
__global__ __launch_bounds__(1024) void xproj_kernel(
    const float* __restrict__ xlin, const float* __restrict__ xac,
    const float* __restrict__ xim, const unsigned short* __restrict__ pack,
    unsigned short* __restrict__ xp)
{
  __shared__ alignas(16) char slds[81920];
  const char* packc = (const char*)pack;
  const int tid = threadIdx.x, lane = tid & 63, w = tid >> 6;
  const int rA = lane & 15, gA = lane >> 4;
  const int mt = w & 7, half = w >> 3;
  const size_t m0 = (size_t)blockIdx.x * 128;
  const int mr = mt * 16;

  for (int p = tid; p < 9600; p += 1024) {
    int row = p/75, d = p - row*75;
    float4 v = *(const float4*)(xlin + (m0+row)*300 + d*4);
    unsigned long long u = (unsigned long long)f2b(v.x)
      | ((unsigned long long)f2b(v.y) << 16)
      | ((unsigned long long)f2b(v.z) << 32)
      | ((unsigned long long)f2b(v.w) << 48);
    *(unsigned long long*)(slds + (((size_t)row*320 + d*4) << 1)) = u;
  }
  for (int p = tid; p < 1280; p += 1024) {
    int row = p/10, cc = 300 + 2*(p - row*10);
    *(unsigned*)(slds + (((size_t)row*320 + cc) << 1)) = 0;
  }
  __syncthreads();
  for (int blk = half*3; blk < half*3 + 3; ++blk) {
    #pragma unroll
    for (int q = 0; q < 4; ++q) {
      f32x4 acc = {0.f,0.f,0.f,0.f};
      int nt = blk*4 + q;
      reg_loop<10>(packc, lane,
        [&](int i){ return 1394 + nt*10 + i; },
        [&](int i, bf16x8 bv){
          bf16x8 a = *(const bf16x8*)(slds + ((((mr+rA)*320) + i*32 + gA*8) << 1));
          acc = MFMA_B16(a, bv, acc);
        });
      #pragma unroll
      for (int j = 0; j < 4; ++j)
        xp[(m0 + mr + gA*4 + j)*960 + blk*64 + q*16 + rA] = f2b(acc[j]);
    }
  }
  __syncthreads();

  for (int p = tid; p < 4736; p += 1024) {
    int row = p/37, d = p - row*37;
    float2 v = *(const float2*)(xac + (m0+row)*74 + d*2);
    unsigned uu = (unsigned)f2b(v.x) | ((unsigned)f2b(v.y) << 16);
    *(unsigned*)(slds + (((size_t)row*96 + d*2) << 1)) = uu;
  }
  for (int p = tid; p < 1408; p += 1024) {
    int row = p/11, cc = 74 + 2*(p - row*11);
    *(unsigned*)(slds + (((size_t)row*96 + cc) << 1)) = 0;
  }
  __syncthreads();
  if (half == 0) {
    for (int blk = 0; blk < 3; ++blk) {
      #pragma unroll
      for (int q = 0; q < 4; ++q) {
        f32x4 acc = {0.f,0.f,0.f,0.f};
        int nt = blk*4 + q;
        reg_loop<3>(packc, lane,
          [&](int i){ return 1634 + nt*3 + i; },
          [&](int i, bf16x8 bv){
            bf16x8 a = *(const bf16x8*)(slds + ((((mr+rA)*96) + i*32 + gA*8) << 1));
            acc = MFMA_B16(a, bv, acc);
          });
        #pragma unroll
        for (int j = 0; j < 4; ++j)
          xp[(m0 + mr + gA*4 + j)*960 + 384 + blk*64 + q*16 + rA] = f2b(acc[j]);
      }
    }
  }
  __syncthreads();

  for (int p = tid; p < 4480; p += 1024) {
    int row = p/35, d = p - row*35;
    *(unsigned short*)(slds + (((size_t)row*64 + d) << 1)) = f2b(xim[(m0+row)*35 + d]);
  }
  for (int p = tid; p < 3712; p += 1024) {
    int row = p/29, cc = 35 + (p - row*29);
    *(unsigned short*)(slds + (((size_t)row*64 + cc) << 1)) = 0;
  }
  __syncthreads();
  if (half == 1) {
    for (int blk = 0; blk < 6; ++blk) {
      #pragma unroll
      for (int q = 0; q < 4; ++q) {
        f32x4 acc = {0.f,0.f,0.f,0.f};
        int nt = blk*4 + q;
        reg_loop<2>(packc, lane,
          [&](int i){ return 1670 + nt*2 + i; },
          [&](int i, bf16x8 bv){
            bf16x8 a = *(const bf16x8*)(slds + ((((mr+rA)*64) + i*32 + gA*8) << 1));
            acc = MFMA_B16(a, bv, acc);
          });
        #pragma unroll
        for (int j = 0; j < 4; ++j)
          xp[(m0 + mr + gA*4 + j)*960 + 576 + blk*64 + q*16 + rA] = f2b(acc[j]);
      }
    }
  }
}

// ---------------------------------------------------------------------------
// Main fused kernel: 8 waves x 512 threads, chunked rings.
// ---------------------------------------------------------------------------
template<int NA,int NB>
__device__ __forceinline__ void twin_gate(f32x4 aA[4], f32x4 aB[4], const char* lds,
    const char* packc, int lane, int rA, int gA,
    int tbA, int hsA, int tbB, int hsB)
{
  reg_loop<(NA+NB)*4>(packc, lane,
    [&](int i){
      if (i < NA*4) { int j = i;        return tbA + (j&3)*NA + (j>>2); }
      else          { int j = i - NA*4; return tbB + (j&3)*NB + (j>>2); }
    },
    [&](int i, bf16x8 bv){
      if (i < NA*4) {
        int q = i & 3, s = i >> 2;
        bf16x8 a = LA(OFF_FEATS,360, rA, hsA + s*32 + gA*8);
        aA[q] = MFMA_B16(a, bv, aA[q]);
      } else {
        int j = i - NA*4, q = j & 3, s = j >> 2;
        bf16x8 a = LA(OFF_FEATS,360, rA, hsB + s*32 + gA*8);
        aB[q] = MFMA_B16(a, bv, aB[q]);
      }
    });
}

template<int NKS>
__device__ __forceinline__ void gate_reg_h(f32x4 acc[4], const char* lds, const char* packc,
    int lane, int rA, int gA, int hsec, int tb)
{
  reg_loop<NKS*4>(packc, lane,
    [&](int i){ return tb + (i & 3)*NKS + (i >> 2); },
    [&](int i, bf16x8 bv){
      int q = i & 3, s = i >> 2;
      bf16x8 a = LA(OFF_FEATS, 360, rA, hsec + s*32 + gA*8);
      acc[q] = MFMA_B16(a, bv, acc[q]);
    });
}

__global__ __launch_bounds__(512, 2) void fused_kernel(
    const unsigned short* __restrict__ pack, const float* __restrict__ biasg,
    const unsigned short* __restrict__ xp, float* __restrict__ out)
{
  __shared__ alignas(16) char lds[LDS_BYTES];
  const char* packc = (const char*)pack;
  const int tid  = threadIdx.x;
  const int lane = tid & 63;
  const int w    = tid >> 6;          // 0..7
  const int rA   = lane & 15;
  const int gA   = lane >> 4;
  const int n0   = blockIdx.x * 16;
  float* biasLds = (float*)(lds + OFF_BIAS);

  for (int i = tid; i < (OFF_BIAS >> 2); i += 512) ((int*)lds)[i] = 0;
  __syncthreads();
  for (int i = tid; i < N_BIAS; i += 512) biasLds[i] = biasg[i];
  {
    const size_t base0 = ((size_t)n0) * 960;
    for (int q = tid; q < 1920; q += 512) {
      int row = q/120, ch = q - row*120;
      ull2 v = __builtin_nontemporal_load((const ull2*)(xp + base0 + (size_t)row*960 + ch*8));
      *(ull2*)(lds + OFF_XP + (((size_t)row*968 + ch*8) << 1)) = v;
    }
  }
  __syncthreads();

  float cstA[4] = {}, cstB[4] = {};
  float mreg[4] = {};

  int tbA, hsA, cbA, HA, blkA;
  if (w < 6)      { tbA = 1226 + w*12; hsA = 0;  cbA = w*64;  HA = 88; blkA = w; }
  else if (w==6)  { tbA = 1298;        hsA = 88; cbA = 384;   HA = 48; blkA = 0; }
  else            { tbA = 1306;        hsA = 88; cbA = 448;   HA = 48; blkA = 1; }
  int tbB, hsB, cbB, HB, blkB;
  if (w == 0)     { tbB = 1314;            hsB = 88;  cbB = 512;          HB = 48; blkB = 2; }
  else            { tbB = 1322 + (w-1)*12; hsB = 136; cbB = 576+(w-1)*64; HB = 88; blkB = w-1; }

  for (int t = 0; t < T_STEPS; ++t) {
    // ---- P1: gates (twin chunked rings) ; w7: gate + out2(t-1) ----
    f32x4 gaccA[4], gaccB[4];
    {
      #pragma unroll
      for (int q = 0; q < 4; ++q) {
        float bvA = biasLds[cbA + q*16 + rA];
        #pragma unroll
        for (int j = 0; j < 4; ++j) {
          int row = gA*4 + j;
          gaccA[q][j] = bvA + b2f(*(const unsigned short*)(lds + OFF_XP + (((size_t)row*968 + cbA + q*16 + rA) << 1)));
        }
        if (w < 7) {
          float bvB = biasLds[cbB + q*16 + rA];
          #pragma unroll
          for (int j = 0; j < 4; ++j) {
            int row = gA*4 + j;
            gaccB[q][j] = bvB + b2f(*(const unsigned short*)(lds + OFF_XP + (((size_t)row*968 + cbB + q*16 + rA) << 1)));
          }
        }
      }
      if (w == 0)      twin_gate<3,2>(gaccA, gaccB, lds, packc, lane, rA, gA, tbA, hsA, tbB, hsB);
      else if (w < 6)  twin_gate<3,3>(gaccA, gaccB, lds, packc, lane, rA, gA, tbA, hsA, tbB, hsB);
      else if (w == 6) twin_gate<2,3>(gaccA, gaccB, lds, packc, lane, rA, gA, tbA, hsA, tbB, hsB);
      else {
        gate_reg_h<2>(gaccA, lds, packc, lane, rA, gA, hsA, tbA);
        if (t > 0) {
          float bv = biasLds[B_OUT2];
          f32x4 oa0 = {bv,bv,bv,bv};
          bf16x8 as[2], bs[2];
          #pragma unroll
          for (int s = 0; s < 2; ++s) { bs[s] = LB(1224 + s); as[s] = LA(OFF_HID,72, rA, s*32+gA*8); }
          #pragma unroll
          for (int s = 0; s < 2; ++s) oa0 = MFMA_B16(as[s], bs[s], oa0);
          if (rA == 0) {
            #pragma unroll
            for (int j = 0; j < 4; ++j)
              __builtin_nontemporal_store(oa0[j], &out[(size_t)(n0 + gA*4 + j)*T_STEPS + (t-1)]);
          }
        }
      }
    }
    __syncthreads();

    // ---- P2: LSTM elementwise (both tasks) ----
    {
      int unitA = blkA*16 + rA;
      if (unitA < HA) {
        #pragma unroll
        for (int j = 0; j < 4; ++j) {
          float iv = sigm (gaccA[0][j]);
          float fv = sigm (gaccA[1][j]);
          float gv = tanh_(gaccA[2][j]);
          float ov = sigm (gaccA[3][j]);
          float cp = cstA[j];
          float cn = fv*cp + iv*gv;
          float hn = ov*tanh_(cn);
          cstA[j] = cn;
          int row = gA*4 + j;
          STB(OFF_CSTAR,456, row, hsA + unitA,        cp);
          STB(OFF_CSTAR,456, row, 224 + hsA + unitA,  cn);
          STB(OFF_FEATS,360, row, hsA + unitA,        hn);
        }
      }
      if (w < 7) {
        int unitB = blkB*16 + rA;
        if (unitB < HB) {
          #pragma unroll
          for (int j = 0; j < 4; ++j) {
            float iv = sigm (gaccB[0][j]);
            float fv = sigm (gaccB[1][j]);
            float gv = tanh_(gaccB[2][j]);
            float ov = sigm (gaccB[3][j]);
            float cp = cstB[j];
            float cn = fv*cp + iv*gv;
            float hn = ov*tanh_(cn);
            cstB[j] = cn;
            int row = gA*4 + j;
            STB(OFF_CSTAR,456, row, hsB + unitB,        cp);
            STB(OFF_CSTAR,456, row, 224 + hsB + unitB,  cn);
            STB(OFF_FEATS,360, row, hsB + unitB,        hn);
          }
        }
      }
    }
    __syncthreads();

    // ---- P3: att1 layer1 (n = w) ----
    {
      int n = w;
      float bv = biasLds[B_A1H + n*16 + rA];
      f32x4 a0v = {bv,bv,bv,bv};
      reg_loop<14>(packc, lane,
        [&](int i){ return 492 + n*14 + i; },
        [&](int i, bf16x8 bv8){
          bf16x8 a = LA(OFF_CSTAR,456, rA, i*32+gA*8);
          a0v = MFMA_B16(a, bv8, a0v);
        });
      #pragma unroll
      for (int j = 0; j < 4; ++j)
        STB(OFF_HID,136, gA*4 + j, n*16 + rA, fmaxf(a0v[j], 0.f));
    }
    __syncthreads();

    // ---- P4: att1 layer2 -> logits ----
    {
      f32x4 l[4];
      #pragma unroll
      for (int k = 0; k < 4; ++k) {
        float bv = biasLds[B_LOG + (w + 8*k)*16 + rA];
        l[k] = (f32x4){bv,bv,bv,bv};
      }
      if (w < 4) {
        reg_loop<16>(packc, lane,
          [&](int i){ return 604 + (w + 8*(i>>2))*4 + (i&3); },
          [&](int i, bf16x8 bv8){
            bf16x8 a = LA(OFF_HID,136, rA, (i&3)*32+gA*8);
            l[i>>2] = MFMA_B16(a, bv8, l[i>>2]);
          });
        #pragma unroll
        for (int k = 0; k < 4; ++k)
          #pragma unroll
          for (int j = 0; j < 4; ++j)
            STB(OFF_ATT,456, gA*4 + j, (w + 8*k)*16 + rA, l[k][j]);
      } else {
        reg_loop<12>(packc, lane,
          [&](int i){ return 604 + (w + 8*(i>>2))*4 + (i&3); },
          [&](int i, bf16x8 bv8){
            bf16x8 a = LA(OFF_HID,136, rA, (i&3)*32+gA*8);
            l[i>>2] = MFMA_B16(a, bv8, l[i>>2]);
          });
        #pragma unroll
        for (int k = 0; k < 3; ++k)
          #pragma unroll
          for (int j = 0; j < 4; ++j)
            STB(OFF_ATT,456, gA*4 + j, (w + 8*k)*16 + rA, l[k][j]);
      }
    }
    __syncthreads();

    // ---- P5: softmax(448)*c_star + nt XP stage (issue early / write late) ----
    {
      ull2 xr[4];
      const bool do_stage = (t < T_STEPS-1);
      const size_t base = ((size_t)(t+1)*2048 + n0)*960;
      if (do_stage) {
        #pragma unroll
        for (int k = 0; k < 4; ++k) {
          int q = tid + k*512;
          if (q < 1920) {
            int row = q/120, ch = q - row*120;
            xr[k] = __builtin_nontemporal_load((const ull2*)(xp + base + (size_t)row*960 + ch*8));
          }
        }
      }
      int row = w*2 + (lane >> 5);
      int cb  = lane & 31;
      float v[14];
      float mx = -3.0e38f;
      #pragma unroll
      for (int q = 0; q < 14; ++q) { v[q] = LDB(OFF_ATT,456,row, cb + 32*q); mx = fmaxf(mx, v[q]); }
      #pragma unroll
      for (int mk = 1; mk < 32; mk <<= 1) mx = fmaxf(mx, __shfl_xor(mx, mk));
      float sm = 0.f;
      #pragma unroll
      for (int q = 0; q < 14; ++q) { v[q] = __expf(v[q] - mx); sm += v[q]; }
      #pragma unroll
      for (int mk = 1; mk < 32; mk <<= 1) sm += __shfl_xor(sm, mk);
      float inv = 1.0f / sm;
      #pragma unroll
      for (int q = 0; q < 14; ++q) {
        int c = cb + 32*q;
        float cs = LDB(OFF_CSTAR,456,row,c);
        STB(OFF_ATT,456,row,c, v[q]*inv*cs);
      }
      if (do_stage) {
        asm volatile("s_waitcnt vmcnt(0)");
        __builtin_amdgcn_sched_barrier(0);
        #pragma unroll
        for (int k = 0; k < 4; ++k) {
          int q = tid + k*512;
          if (q < 1920) {
            int row2 = q/120, ch = q - row2*120;
            *(ull2*)(lds + OFF_XP + (((size_t)row2*968 + ch*8) << 1)) = xr[k];
          }
        }
      }
    }
    __syncthreads();

    // ---- P6: att2 layer1 (2 tiles) + g1/g2 (1 tile), fused chunked ring ----
    {
      int nb = w*2;
      int which = w >> 2, n = w & 3;
      int tbq = which ? 1076 : 1004;
      int bb  = which ? B_G2H : B_G1H;
      int oo  = which ? OFF_G2H : OFF_G1H;
      float b0 = biasLds[B_A2H + nb*16 + rA];
      float b1 = biasLds[B_A2H + (nb+1)*16 + rA];
      float bg = biasLds[bb + n*16 + rA];
      f32x4 A0 = {b0,b0,b0,b0}, A1 = {b1,b1,b1,b1}, G = {bg,bg,bg,bg};
      reg_loop<46>(packc, lane,
        [&](int i){
          if (i < 14) return 716 + nb*14 + i;
          if (i < 28) return 716 + (nb+1)*14 + (i-14);
          return tbq + n*18 + (i-28);
        },
        [&](int i, bf16x8 bv8){
          if (i < 14) {
            bf16x8 a = LA(OFF_ATT,456, rA, i*32+gA*8);
            A0 = MFMA_B16(a, bv8, A0);
          } else if (i < 28) {
            int s = i - 14;
            bf16x8 a = LA(OFF_ATT,456, rA, s*32+gA*8);
            A1 = MFMA_B16(a, bv8, A1);
          } else {
            int s = i - 28;
            bf16x8 a = (s < 14) ? LA(OFF_ATT,456, rA, s*32+gA*8)
                                : LA(OFF_FEATS,360, rA, 224 + (s-14)*32 + gA*8);
            G = MFMA_B16(a, bv8, G);
          }
        });
      #pragma unroll
      for (int j = 0; j < 4; ++j) {
        STB(OFF_HID,264, gA*4 + j, nb*16 + rA,     fmaxf(A0[j], 0.f));
        STB(OFF_HID,264, gA*4 + j, (nb+1)*16 + rA, fmaxf(A1[j], 0.f));
        STB(oo,72,       gA*4 + j, n*16 + rA,      fmaxf(G[j],  0.f));
      }
    }
    __syncthreads();

    // ---- P7: att2 layer2 (tanh) + gammas + mem (n = w) ----
    {
      int n = w;
      float bc = biasLds[B_CHAT + n*16 + rA];
      float b1 = biasLds[B_GM1  + n*16 + rA];
      float b2 = biasLds[B_GM2  + n*16 + rA];
      f32x4 cc0={bc,bc,bc,bc};
      f32x4 g10={b1,b1,b1,b1};
      f32x4 g20={b2,b2,b2,b2};
      reg_loop<12>(packc, lane,
        [&](int i){
          if (i < 8)  return 940 + n*8 + i;
          if (i < 10) return 1148 + n*2 + (i - 8);
          return 1164 + n*2 + (i - 10);
        },
        [&](int i, bf16x8 bv8){
          if (i < 8) {
            bf16x8 a = LA(OFF_HID,264, rA, i*32+gA*8);
            cc0 = MFMA_B16(a, bv8, cc0);
          } else if (i < 10) {
            bf16x8 a = LA(OFF_G1H,72, rA, (i-8)*32+gA*8);
            g10 = MFMA_B16(a, bv8, g10);
          } else {
            bf16x8 a = LA(OFF_G2H,72, rA, (i-10)*32+gA*8);
            g20 = MFMA_B16(a, bv8, g20);
          }
        });
      #pragma unroll
      for (int j = 0; j < 4; ++j) {
        float ch = tanh_(cc0[j]), ga = sigm(g10[j]), gb = sigm(g20[j]);
        float mn = ga*mreg[j] + gb*ch;
        mreg[j] = mn;
        STB(OFF_FEATS,360, gA*4 + j, 224 + n*16 + rA, mn);
      }
    }
    __syncthreads();

    // ---- P8: out layer1 (w<4) ----
    if (w < 4) {
      int n = w;
      float bv = biasLds[B_OUTH + n*16 + rA];
      f32x4 a0v = {bv,bv,bv,bv};
      reg_loop<11>(packc, lane,
        [&](int i){ return 1180 + n*11 + i; },
        [&](int i, bf16x8 bv8){
          bf16x8 a = LA(OFF_FEATS,360, rA, i*32+gA*8);
          a0v = MFMA_B16(a, bv8, a0v);
        });
      #pragma unroll
      for (int j = 0; j < 4; ++j)
        STB(OFF_HID,72, gA*4 + j, n*16 + rA, fmaxf(a0v[j], 0.f));
    }
    __syncthreads();
  }

  // ---- Final out2 (t = 127) ----
  if (w == 7) {
    float bv = biasLds[B_OUT2];
    f32x4 oa0 = {bv,bv,bv,bv};
    bf16x8 as[2], bs[2];
    #pragma unroll
    for (int s = 0; s < 2; ++s) { bs[s] = LB(1224 + s); as[s] = LA(OFF_HID,72, rA, s*32+gA*8); }
    #pragma unroll
    for (int s = 0; s < 2; ++s) oa0 = MFMA_B16(as[s], bs[s], oa0);
    if (rA == 0) {
      #pragma unroll
      for (int j = 0; j < 4; ++j)
        __builtin_nontemporal_store(oa0[j], &out[(size_t)(n0 + gA*4 + j)*T_STEPS + 127]);
    }
  }
}

extern "C" void kernel_launch(void* const* d_in, const int* in_sizes, int n_in,
                              void* d_out, int out_size, void* d_ws, size_t ws_size,
                              hipStream_t stream) {
  (void)in_sizes; (void)n_in; (void)out_size; (void)ws_size;
  PP P;
  for (int i = 0; i < 35; ++i) P.p[i] = (const float*)d_in[i];
  unsigned short* pack = (unsigned short*)d_ws;
  float* bias = (float*)((char*)d_ws + PACK_BYTES);
  unsigned short* xp = (unsigned short*)((char*)d_ws + PACK_BYTES + 16384);

  hipLaunchKernelGGL(pack_kernel, dim3(320), dim3(256), 0, stream, P, pack, bias);
  hipLaunchKernelGGL(xproj_kernel, dim3(2048), dim3(1024), 0, stream,
                     P.p[0], P.p[1], P.p[2], pack, xp);
  hipLaunchKernelGGL(fused_kernel, dim3(128), dim3(512), 0, stream,
                     pack, bias, xp, (float*)d_out);
}

// Round 16
// 4044.646 us; speedup vs baseline: 1.4772x; 1.4772x over previous
//
#include <hip/hip_runtime.h>

// ---------------------------------------------------------------------------
// Fused recurrent multimodal net. T=128, N=2048. 128 blocks x 16 rows.
// Round 15: r12 base (best measured: 16 waves, depth-8 reg rings, XP hoist)
// + nontemporal XP staging (r13-verified: keeps 1.7MB pack L2-resident,
// FETCH 1.05GB -> ~0.56GB). r14's chunked waits spilled (WRITE 788MB) and
// is reverted. Single variable vs r12.
// ---------------------------------------------------------------------------

#define T_STEPS 128

typedef __attribute__((ext_vector_type(8))) short bf16x8;
typedef __attribute__((ext_vector_type(4))) float f32x4;
typedef __attribute__((ext_vector_type(2))) unsigned long long ull2;

#define MFMA_B16(a,b,c) __builtin_amdgcn_mfma_f32_16x16x32_bf16((a),(b),(c),0,0,0)

__device__ __forceinline__ unsigned short f2b(float v) {
  union { float f; unsigned u; } x; x.f = v;
  unsigned r = x.u + 0x7fffu + ((x.u >> 16) & 1u);
  return (unsigned short)(r >> 16);
}
__device__ __forceinline__ float b2f(unsigned short u) {
  union { unsigned u; float f; } x; x.u = ((unsigned)u) << 16; return x.f;
}
__device__ __forceinline__ float sigm(float x){ return 1.0f/(1.0f + __expf(-x)); }
__device__ __forceinline__ float tanh_(float x){ return 1.0f - 2.0f/(1.0f + __expf(2.0f*x)); }

// ---- core LDS layout ----
#define OFF_XL     0
#define OFF_XA     10496
#define OFF_XI     13824
#define OFF_CSTAR  16128
#define OFF_ATT    30720
#define OFF_HID    45312
#define OFF_G1H    53760
#define OFF_G2H    56064
#define OFF_FEATS  58368
#define OFF_BIAS   69888
#define OFF_XP     79368    // 16 x 968 bf16
#define LDS_BYTES  110344   // >80KB: 1 block/CU

// ---- bias layout ----
#define BG_LIN 0
#define BG_AC  384
#define BG_IM  576
#define B_A1H  960
#define B_LOG  1088
#define B_A2H  1536
#define B_CHAT 1792
#define B_G1H  1920
#define B_G2H  1984
#define B_GM1  2048
#define B_GM2  2176
#define B_OUTH 2304
#define B_OUT2 2368
#define N_BIAS 2369

#define N_TILES 1718
#define PACK_BYTES ((size_t)N_TILES * 1024)
#define XP_ELEMS ((size_t)262144 * 960)
#define XP_BYTES (XP_ELEMS * 2)

#define LA(off,st,row,kk)  (*(const bf16x8*)(lds + (off) + ((((row)*(st)) + (kk)) << 1)))
#define LB(tile)           (*(const bf16x8*)(packc + (((size_t)(tile)) << 10) + (lane << 4)))
#define STB(off,st,row,col,v) (*(unsigned short*)(lds + (off) + ((((row)*(st)) + (col)) << 1)) = f2b(v))
#define LDB(off,st,row,col)   b2f(*(const unsigned short*)(lds + (off) + ((((row)*(st)) + (col)) << 1)))

struct PP { const float* p[35]; };

// ---------------------------------------------------------------------------
// Register async-pipeline primitives (r8/r12: depth-8, issue-1/consume-1)
// ---------------------------------------------------------------------------
__device__ __forceinline__ void vmw(int n) {
  switch (n) {
    case 0: asm volatile("s_waitcnt vmcnt(0)"); break;
    case 1: asm volatile("s_waitcnt vmcnt(1)"); break;
    case 2: asm volatile("s_waitcnt vmcnt(2)"); break;
    case 3: asm volatile("s_waitcnt vmcnt(3)"); break;
    case 4: asm volatile("s_waitcnt vmcnt(4)"); break;
    case 5: asm volatile("s_waitcnt vmcnt(5)"); break;
    case 6: asm volatile("s_waitcnt vmcnt(6)"); break;
    default: asm volatile("s_waitcnt vmcnt(7)"); break;
  }
  __builtin_amdgcn_sched_barrier(0);
}

#define ISSUE_B(dst, tile)                                                   \
  { unsigned off_ = (((unsigned)(tile)) << 10) + ((unsigned)lane << 4);      \
    asm volatile("global_load_dwordx4 %0, %1, %2"                            \
                 : "=v"(dst) : "v"(off_), "s"(packc)); }

template<int NTT, class FT, class FB>
__device__ __forceinline__ void reg_loop(const char* packc, int lane,
                                         FT&& tile_of, FB&& body)
{
  constexpr int D = (NTT < 8) ? NTT : 8;
  bf16x8 b[8];
  #pragma unroll
  for (int i = 0; i < D; ++i) ISSUE_B(b[i], tile_of(i));
  #pragma unroll
  for (int i = 0; i < NTT; ++i) {
    vmw((NTT-1-i) < 7 ? (NTT-1-i) : 7);
    body(i, b[i & 7]);
    __builtin_amdgcn_sched_barrier(0);
    if (i + 8 < NTT) ISSUE_B(b[i & 7], tile_of(i + 8));
  }
}

// ---------------------------------------------------------------------------
// Pack kernel: old tiles + h-only gate tiles + x-projection tiles + biases.
// ---------------------------------------------------------------------------
__device__ __forceinline__ float gate_src(const float* Wih, const float* Whh,
                                          int H, int din, int nksx, int col, int k)
{
  int blk = col >> 6, gate = (col >> 4) & 3, u = col & 15;
  int unit = blk*16 + u;
  if (unit >= H) return 0.f;
  int row = gate*H + unit;
  int xk = nksx*32;
  if (k < xk) return (k < din) ? Wih[row*din + k] : 0.f;
  int kk = k - xk;
  return (kk < H) ? Whh[row*H + kk] : 0.f;
}
__device__ __forceinline__ float gate_h(const float* Whh, int H, int col, int k)
{
  int blk = col >> 6, gate = (col >> 4) & 3, u = col & 15;
  int unit = blk*16 + u;
  if (unit >= H || k >= H) return 0.f;
  return Whh[(gate*H + unit)*H + k];
}
__device__ __forceinline__ float gate_x(const float* Wih, int H, int din, int col, int k)
{
  int blk = col >> 6, gate = (col >> 4) & 3, u = col & 15;
  int unit = blk*16 + u;
  if (unit >= H || k >= din) return 0.f;
  return Wih[(gate*H + unit)*din + k];
}
__device__ __forceinline__ float plain_src(const float* W, int nout, int kdim, int col, int k)
{
  return (col < nout && k < kdim) ? W[col*kdim + k] : 0.f;
}

__global__ __launch_bounds__(256) void pack_kernel(PP P, unsigned short* __restrict__ pack,
                                                   float* __restrict__ bias)
{
  int tid = blockIdx.x*blockDim.x + threadIdx.x;
  int wv = tid >> 6, lane = tid & 63;
  int nw = (gridDim.x*blockDim.x) >> 6;
  int c = lane & 15, kg = lane >> 4;

  for (int tile = wv; tile < N_TILES; tile += nw) {
    unsigned short* dst = pack + ((size_t)tile << 9) + lane*8;
    #pragma unroll
    for (int i = 0; i < 8; ++i) {
      int r = tile; int nt, ks; float v; int kk;
      if (r < 312)       { nt=r/13; ks=r-nt*13; kk=ks*32+kg*8+i; v = gate_src(P.p[3], P.p[4], 88,300,10, nt*16+c, kk); }
      else if (r < 372)  { r-=312; nt=r/5;  ks=r-nt*5;  kk=ks*32+kg*8+i; v = gate_src(P.p[7], P.p[8], 48, 74, 3, nt*16+c, kk); }
      else if (r < 492)  { r-=372; nt=r/5;  ks=r-nt*5;  kk=ks*32+kg*8+i; v = gate_src(P.p[11],P.p[12],88, 35, 2, nt*16+c, kk); }
      else if (r < 604)  { r-=492; nt=r/14; ks=r-nt*14; kk=ks*32+kg*8+i; v = plain_src(P.p[15],128,448, nt*16+c, kk); }
      else if (r < 716)  { r-=604; nt=r/4;  ks=r-nt*4;  kk=ks*32+kg*8+i; v = plain_src(P.p[17],448,128, nt*16+c, kk); }
      else if (r < 940)  { r-=716; nt=r/14; ks=r-nt*14; kk=ks*32+kg*8+i; v = plain_src(P.p[19],256,448, nt*16+c, kk); }
      else if (r < 1004) { r-=940; nt=r/8;  ks=r-nt*8;  kk=ks*32+kg*8+i; v = plain_src(P.p[21],128,256, nt*16+c, kk); }
      else if (r < 1076) { r-=1004; nt=r/18; ks=r-nt*18; kk=ks*32+kg*8+i; v = plain_src(P.p[23], 64,576, nt*16+c, kk); }
      else if (r < 1148) { r-=1076; nt=r/18; ks=r-nt*18; kk=ks*32+kg*8+i; v = plain_src(P.p[27], 64,576, nt*16+c, kk); }
      else if (r < 1164) { r-=1148; nt=r/2;  ks=r-nt*2;  kk=ks*32+kg*8+i; v = plain_src(P.p[25],128, 64, nt*16+c, kk); }
      else if (r < 1180) { r-=1164; nt=r/2;  ks=r-nt*2;  kk=ks*32+kg*8+i; v = plain_src(P.p[29],128, 64, nt*16+c, kk); }
      else if (r < 1224) { r-=1180; nt=r/11; ks=r-nt*11; kk=ks*32+kg*8+i; v = plain_src(P.p[31], 64,352, nt*16+c, kk); }
      else if (r < 1226) { r-=1224; ks=r;    kk=ks*32+kg*8+i; v = plain_src(P.p[33],  1, 64, c, kk); }
      else if (r < 1298) { r-=1226; nt=r/3;  ks=r-nt*3;  kk=ks*32+kg*8+i; v = gate_h(P.p[4], 88, nt*16+c, kk); }
      else if (r < 1322) { r-=1298; nt=r/2;  ks=r-nt*2;  kk=ks*32+kg*8+i; v = gate_h(P.p[8], 48, nt*16+c, kk); }
      else if (r < 1394) { r-=1322; nt=r/3;  ks=r-nt*3;  kk=ks*32+kg*8+i; v = gate_h(P.p[12],88, nt*16+c, kk); }
      else if (r < 1634) { r-=1394; nt=r/10; ks=r-nt*10; kk=ks*32+kg*8+i; v = gate_x(P.p[3], 88,300, nt*16+c, kk); }
      else if (r < 1670) { r-=1634; nt=r/3;  ks=r-nt*3;  kk=ks*32+kg*8+i; v = gate_x(P.p[7], 48, 74, nt*16+c, kk); }
      else               { r-=1670; nt=r/2;  ks=r-nt*2;  kk=ks*32+kg*8+i; v = gate_x(P.p[11],88, 35, nt*16+c, kk); }
      dst[i] = f2b(v);
    }
  }

  int NT = gridDim.x*blockDim.x;
  for (int b = tid; b < N_BIAS; b += NT) {
    float v; int r = b;
    if (r < 384)       { int blk=r>>6, g=(r>>4)&3, u=r&15, un=blk*16+u; v = (un<88) ? P.p[5][g*88+un] + P.p[6][g*88+un]  : 0.f; }
    else if (r < 576)  { r-=384; int blk=r>>6, g=(r>>4)&3, u=r&15, un=blk*16+u; v = (un<48) ? P.p[9][g*48+un] + P.p[10][g*48+un] : 0.f; }
    else if (r < 960)  { r-=576; int blk=r>>6, g=(r>>4)&3, u=r&15, un=blk*16+u; v = (un<88) ? P.p[13][g*88+un]+ P.p[14][g*88+un] : 0.f; }
    else if (r < 1088) v = P.p[16][r-960];
    else if (r < 1536) v = P.p[18][r-1088];
    else if (r < 1792) v = P.p[20][r-1536];
    else if (r < 1920) v = P.p[22][r-1792];
    else if (r < 1984) v = P.p[24][r-1920];
    else if (r < 2048) v = P.p[28][r-1984];
    else if (r < 2176) v = P.p[26][r-2048];
    else if (r < 2304) v = P.p[30][r-2176];
    else if (r < 2368) v = P.p[32][r-2304];
    else               v = P.p[34][0];
    bias[b] = v;
  }
}

// ---------------------------------------------------------------------------
// XP pre-pass (r12, unchanged)
// ---------------------------------------------------------------------------
__global__ __launch_bounds__(1024) void xproj_kernel(
    const float* __restrict__ xlin, const float* __restrict__ xac,
    const float* __restrict__ xim, const unsigned short* __restrict__ pack,
    unsigned short* __restrict__ xp)
{
  __shared__ alignas(16) char slds[81920];
  const char* packc = (const char*)pack;
  const int tid = threadIdx.x, lane = tid & 63, w = tid >> 6;
  const int rA = lane & 15, gA = lane >> 4;
  const int mt = w & 7, half = w >> 3;
  const size_t m0 = (size_t)blockIdx.x * 128;
  const int mr = mt * 16;

  for (int p = tid; p < 9600; p += 1024) {
    int row = p/75, d = p - row*75;
    float4 v = *(const float4*)(xlin + (m0+row)*300 + d*4);
    unsigned long long u = (unsigned long long)f2b(v.x)
      | ((unsigned long long)f2b(v.y) << 16)
      | ((unsigned long long)f2b(v.z) << 32)
      | ((unsigned long long)f2b(v.w) << 48);
    *(unsigned long long*)(slds + (((size_t)row*320 + d*4) << 1)) = u;
  }
  for (int p = tid; p < 1280; p += 1024) {
    int row = p/10, cc = 300 + 2*(p - row*10);
    *(unsigned*)(slds + (((size_t)row*320 + cc) << 1)) = 0;
  }
  __syncthreads();
  for (int blk = half*3; blk < half*3 + 3; ++blk) {
    #pragma unroll
    for (int q = 0; q < 4; ++q) {
      f32x4 acc = {0.f,0.f,0.f,0.f};
      int nt = blk*4 + q;
      bf16x8 a = *(const bf16x8*)(slds + ((((mr+rA)*320) + gA*8) << 1));
      reg_loop<10>(packc, lane,
        [&](int i){ return 1394 + nt*10 + i; },
        [&](int i, bf16x8 bv){
          acc = MFMA_B16(a, bv, acc);
          if (i + 1 < 10) a = *(const bf16x8*)(slds + ((((mr+rA)*320) + (i+1)*32 + gA*8) << 1));
        });
      #pragma unroll
      for (int j = 0; j < 4; ++j)
        xp[(m0 + mr + gA*4 + j)*960 + blk*64 + q*16 + rA] = f2b(acc[j]);
    }
  }
  __syncthreads();

  for (int p = tid; p < 4736; p += 1024) {
    int row = p/37, d = p - row*37;
    float2 v = *(const float2*)(xac + (m0+row)*74 + d*2);
    unsigned uu = (unsigned)f2b(v.x) | ((unsigned)f2b(v.y) << 16);
    *(unsigned*)(slds + (((size_t)row*96 + d*2) << 1)) = uu;
  }
  for (int p = tid; p < 1408; p += 1024) {
    int row = p/11, cc = 74 + 2*(p - row*11);
    *(unsigned*)(slds + (((size_t)row*96 + cc) << 1)) = 0;
  }
  __syncthreads();
  if (half == 0) {
    for (int blk = 0; blk < 3; ++blk) {
      #pragma unroll
      for (int q = 0; q < 4; ++q) {
        f32x4 acc = {0.f,0.f,0.f,0.f};
        int nt = blk*4 + q;
        bf16x8 a = *(const bf16x8*)(slds + ((((mr+rA)*96) + gA*8) << 1));
        reg_loop<3>(packc, lane,
          [&](int i){ return 1634 + nt*3 + i; },
          [&](int i, bf16x8 bv){
            acc = MFMA_B16(a, bv, acc);
            if (i + 1 < 3) a = *(const bf16x8*)(slds + ((((mr+rA)*96) + (i+1)*32 + gA*8) << 1));
          });
        #pragma unroll
        for (int j = 0; j < 4; ++j)
          xp[(m0 + mr + gA*4 + j)*960 + 384 + blk*64 + q*16 + rA] = f2b(acc[j]);
      }
    }
  }
  __syncthreads();

  for (int p = tid; p < 4480; p += 1024) {
    int row = p/35, d = p - row*35;
    *(unsigned short*)(slds + (((size_t)row*64 + d) << 1)) = f2b(xim[(m0+row)*35 + d]);
  }
  for (int p = tid; p < 3712; p += 1024) {
    int row = p/29, cc = 35 + (p - row*29);
    *(unsigned short*)(slds + (((size_t)row*64 + cc) << 1)) = 0;
  }
  __syncthreads();
  if (half == 1) {
    for (int blk = 0; blk < 6; ++blk) {
      #pragma unroll
      for (int q = 0; q < 4; ++q) {
        f32x4 acc = {0.f,0.f,0.f,0.f};
        int nt = blk*4 + q;
        bf16x8 a = *(const bf16x8*)(slds + ((((mr+rA)*64) + gA*8) << 1));
        reg_loop<2>(packc, lane,
          [&](int i){ return 1670 + nt*2 + i; },
          [&](int i, bf16x8 bv){
            acc = MFMA_B16(a, bv, acc);
            if (i + 1 < 2) a = *(const bf16x8*)(slds + ((((mr+rA)*64) + 32 + gA*8) << 1));
          });
        #pragma unroll
        for (int j = 0; j < 4; ++j)
          xp[(m0 + mr + gA*4 + j)*960 + 576 + blk*64 + q*16 + rA] = f2b(acc[j]);
      }
    }
  }
}

// ---------------------------------------------------------------------------
// Main fused kernel (r12 structure, 16 waves; nt XP staging)
// ---------------------------------------------------------------------------
template<int NKS>
__device__ __forceinline__ void gate_reg_h(f32x4 acc[4], const char* lds, const char* packc,
    int lane, int rA, int gA, int hsec, int tb)
{
  bf16x8 a;
  reg_loop<NKS*4>(packc, lane,
    [&](int i){ return tb + (i & 3)*NKS + (i >> 2); },
    [&](int i, bf16x8 bv){
      int q = i & 3, s = i >> 2;
      if (q == 0) a = LA(OFF_FEATS, 360, rA, hsec + s*32 + gA*8);
      acc[q] = MFMA_B16(a, bv, acc[q]);
    });
}

__device__ __forceinline__ void stage_xp(char* lds, const unsigned short* __restrict__ xp,
                                         int t, int n0, int tid0, int nthr)
{
  const size_t base = ((size_t)t*2048 + n0)*960;
  for (int q = tid0; q < 1920; q += nthr) {
    int row = q/120, ch = q - row*120;
    ull2 v = __builtin_nontemporal_load((const ull2*)(xp + base + (size_t)row*960 + ch*8));
    *(ull2*)(lds + OFF_XP + (((size_t)row*968 + ch*8) << 1)) = v;
  }
}

__global__ __launch_bounds__(1024) void fused_kernel(
    const unsigned short* __restrict__ pack, const float* __restrict__ biasg,
    const unsigned short* __restrict__ xp, float* __restrict__ out)
{
  __shared__ alignas(16) char lds[LDS_BYTES];
  const char* packc = (const char*)pack;
  const int tid  = threadIdx.x;
  const int lane = tid & 63;
  const int w    = tid >> 6;
  const int rA   = lane & 15;
  const int gA   = lane >> 4;
  const int n0   = blockIdx.x * 16;
  float* biasLds = (float*)(lds + OFF_BIAS);

  for (int i = tid; i < (OFF_BIAS >> 2); i += 1024) ((int*)lds)[i] = 0;
  __syncthreads();
  for (int i = tid; i < N_BIAS; i += 1024) biasLds[i] = biasg[i];
  stage_xp(lds, xp, 0, n0, tid, 1024);
  __syncthreads();

  float cst[4]  = {};
  float mreg[4] = {};

  for (int t = 0; t < T_STEPS; ++t) {
    // ---- Phase 1: gate matmuls (w0..14, h-only, XP-init); w15: out2(t-1) ----
    f32x4 gacc[4];
    if (w == 15) {
      if (t > 0) {
        float bv = biasLds[B_OUT2];
        f32x4 oa0 = {bv,bv,bv,bv};
        bf16x8 as[2], bs[2];
        #pragma unroll
        for (int s = 0; s < 2; ++s) { bs[s] = LB(1224 + s); as[s] = LA(OFF_HID,72, rA, s*32+gA*8); }
        #pragma unroll
        for (int s = 0; s < 2; ++s) oa0 = MFMA_B16(as[s], bs[s], oa0);
        if (rA == 0) {
          #pragma unroll
          for (int j = 0; j < 4; ++j)
            __builtin_nontemporal_store(oa0[j], &out[(size_t)(n0 + gA*4 + j)*T_STEPS + (t-1)]);
        }
      }
    } else {
      int blk, tb, nks, hsec, bb, cb;
      if (w < 6)      { blk=w;   tb=1226+w*12;      nks=3; hsec=0;   bb=BG_LIN; cb=0   + w*64; }
      else if (w < 9) { blk=w-6; tb=1298+(w-6)*8;   nks=2; hsec=88;  bb=BG_AC;  cb=384 + (w-6)*64; }
      else            { blk=w-9; tb=1322+(w-9)*12;  nks=3; hsec=136; bb=BG_IM;  cb=576 + (w-9)*64; }
      #pragma unroll
      for (int q = 0; q < 4; ++q) {
        float bv = biasLds[bb + blk*64 + q*16 + rA];
        #pragma unroll
        for (int j = 0; j < 4; ++j) {
          int row = gA*4 + j;
          float xv = b2f(*(const unsigned short*)(lds + OFF_XP + (((size_t)row*968 + cb + q*16 + rA) << 1)));
          gacc[q][j] = bv + xv;
        }
      }
      if (nks == 3) gate_reg_h<3>(gacc, lds, packc, lane, rA, gA, hsec, tb);
      else          gate_reg_h<2>(gacc, lds, packc, lane, rA, gA, hsec, tb);
    }
    __syncthreads();

    // ---- Phase 2: LSTM elementwise ----
    if (w < 15) {
      int blk, hsec, H;
      if (w < 6)      { blk=w;   hsec=0;   H=88; }
      else if (w < 9) { blk=w-6; hsec=88;  H=48; }
      else            { blk=w-9; hsec=136; H=88; }
      int unit = blk*16 + rA;
      if (unit < H) {
        #pragma unroll
        for (int j = 0; j < 4; ++j) {
          float iv = sigm (gacc[0][j]);
          float fv = sigm (gacc[1][j]);
          float gv = tanh_(gacc[2][j]);
          float ov = sigm (gacc[3][j]);
          float cp = cst[j];
          float cn = fv*cp + iv*gv;
          float hn = ov*tanh_(cn);
          cst[j] = cn;
          int row = gA*4 + j;
          STB(OFF_CSTAR,456, row, hsec + unit,        cp);
          STB(OFF_CSTAR,456, row, 224 + hsec + unit,  cn);
          STB(OFF_FEATS,360, row, hsec + unit,        hn);
        }
      }
    }
    __syncthreads();

    // ---- Phase 3: att1 layer1 ----
    if (w < 8) {
      int n = w;
      float bv = biasLds[B_A1H + n*16 + rA];
      f32x4 a0v = {bv,bv,bv,bv};
      bf16x8 a = LA(OFF_CSTAR,456, rA, gA*8);
      reg_loop<14>(packc, lane,
        [&](int i){ return 492 + n*14 + i; },
        [&](int i, bf16x8 bv8){
          a0v = MFMA_B16(a, bv8, a0v);
          if (i + 1 < 14) a = LA(OFF_CSTAR,456, rA, (i+1)*32+gA*8);
        });
      #pragma unroll
      for (int j = 0; j < 4; ++j)
        STB(OFF_HID,136, gA*4 + j, n*16 + rA, fmaxf(a0v[j], 0.f));
    }
    __syncthreads();

    // ---- Phase 4: att1 layer2 -> logits ----
    {
      float bv1 = biasLds[B_LOG + w*16 + rA];
      if (w < 12) {
        float bv2 = biasLds[B_LOG + (w+16)*16 + rA];
        f32x4 l0 = {bv1,bv1,bv1,bv1}, l1 = {bv2,bv2,bv2,bv2};
        bf16x8 a = LA(OFF_HID,136, rA, gA*8);
        reg_loop<8>(packc, lane,
          [&](int i){ int tau = (i < 4) ? w : (w + 16); return 604 + tau*4 + (i & 3); },
          [&](int i, bf16x8 bv8){
            if (i < 4) l0 = MFMA_B16(a, bv8, l0); else l1 = MFMA_B16(a, bv8, l1);
            if (i + 1 < 8) a = LA(OFF_HID,136, rA, ((i+1)&3)*32+gA*8);
          });
        #pragma unroll
        for (int j = 0; j < 4; ++j) {
          STB(OFF_ATT,456, gA*4 + j, w*16 + rA,      l0[j]);
          STB(OFF_ATT,456, gA*4 + j, (w+16)*16 + rA, l1[j]);
        }
      } else {
        f32x4 l0 = {bv1,bv1,bv1,bv1};
        bf16x8 a = LA(OFF_HID,136, rA, gA*8);
        reg_loop<4>(packc, lane,
          [&](int i){ return 604 + w*4 + i; },
          [&](int i, bf16x8 bv8){
            l0 = MFMA_B16(a, bv8, l0);
            if (i + 1 < 4) a = LA(OFF_HID,136, rA, (i+1)*32+gA*8);
          });
        #pragma unroll
        for (int j = 0; j < 4; ++j)
          STB(OFF_ATT,456, gA*4 + j, w*16 + rA, l0[j]);
      }
    }
    __syncthreads();

    // ---- Phase 5: softmax*c_star (w<8) ; nt XP stage for t+1 (w>=8) ----
    if (w < 8) {
      int row = w*2 + (lane >> 5);
      int cb  = lane & 31;
      float v[14];
      float mx = -3.0e38f;
      #pragma unroll
      for (int q = 0; q < 14; ++q) { v[q] = LDB(OFF_ATT,456,row, cb + 32*q); mx = fmaxf(mx, v[q]); }
      #pragma unroll
      for (int mk = 1; mk < 32; mk <<= 1) mx = fmaxf(mx, __shfl_xor(mx, mk));
      float sm = 0.f;
      #pragma unroll
      for (int q = 0; q < 14; ++q) { v[q] = __expf(v[q] - mx); sm += v[q]; }
      #pragma unroll
      for (int mk = 1; mk < 32; mk <<= 1) sm += __shfl_xor(sm, mk);
      float inv = 1.0f / sm;
      #pragma unroll
      for (int q = 0; q < 14; ++q) {
        int c = cb + 32*q;
        float cs = LDB(OFF_CSTAR,456,row,c);
        STB(OFF_ATT,456,row,c, v[q]*inv*cs);
      }
    } else if (t < T_STEPS-1) {
      stage_xp(lds, xp, t+1, n0, tid - 512, 512);
    }
    __syncthreads();

    // ---- Phase 6: att2 layer1 (w8-15, 2 n-tiles); g1/g2 (w0-7) ----
    if (w >= 8) {
      int nb = (w - 8)*2;
      float b0 = biasLds[B_A2H + nb*16 + rA];
      float b1 = biasLds[B_A2H + (nb+1)*16 + rA];
      f32x4 A0 = {b0,b0,b0,b0}, A1 = {b1,b1,b1,b1};
      bf16x8 a = LA(OFF_ATT,456, rA, gA*8);
      reg_loop<28>(packc, lane,
        [&](int i){ int rr = (i >= 14) ? 1 : 0; int s = i - (rr ? 14 : 0); return 716 + (nb+rr)*14 + s; },
        [&](int i, bf16x8 bv8){
          if (i < 14) A0 = MFMA_B16(a, bv8, A0); else A1 = MFMA_B16(a, bv8, A1);
          if (i + 1 < 28) {
            int ns = (i + 1 < 14) ? (i + 1) : (i + 1 - 14);
            a = LA(OFF_ATT,456, rA, ns*32+gA*8);
          }
        });
      #pragma unroll
      for (int j = 0; j < 4; ++j) {
        STB(OFF_HID,264, gA*4 + j, nb*16 + rA,     fmaxf(A0[j], 0.f));
        STB(OFF_HID,264, gA*4 + j, (nb+1)*16 + rA, fmaxf(A1[j], 0.f));
      }
    } else {
      int which = w >> 2;
      int n = w & 3;
      int tbq = which ? 1076 : 1004;
      int bb  = which ? B_G2H : B_G1H;
      int oo  = which ? OFF_G2H : OFF_G1H;
      float bv = biasLds[bb + n*16 + rA];
      f32x4 A0 = {bv,bv,bv,bv};
      bf16x8 a = LA(OFF_ATT,456, rA, gA*8);
      reg_loop<18>(packc, lane,
        [&](int i){ return tbq + n*18 + i; },
        [&](int i, bf16x8 bv8){
          A0 = MFMA_B16(a, bv8, A0);
          if (i + 1 < 18) {
            a = (i + 1 < 14) ? LA(OFF_ATT,456, rA, (i+1)*32+gA*8)
                             : LA(OFF_FEATS,360, rA, 224 + (i+1-14)*32 + gA*8);
          }
        });
      #pragma unroll
      for (int j = 0; j < 4; ++j)
        STB(oo,72, gA*4 + j, n*16 + rA, fmaxf(A0[j], 0.f));
    }
    __syncthreads();

    // ---- Phase 7: att2 layer2 + gammas + mem ----
    if (w < 8) {
      int n = w;
      float bc = biasLds[B_CHAT + n*16 + rA];
      float b1 = biasLds[B_GM1  + n*16 + rA];
      float b2 = biasLds[B_GM2  + n*16 + rA];
      f32x4 cc0={bc,bc,bc,bc};
      f32x4 g10={b1,b1,b1,b1};
      f32x4 g20={b2,b2,b2,b2};
      bf16x8 a = LA(OFF_HID,264, rA, gA*8);
      reg_loop<12>(packc, lane,
        [&](int i){
          if (i < 8)  return 940 + n*8 + i;
          if (i < 10) return 1148 + n*2 + (i - 8);
          return 1164 + n*2 + (i - 10);
        },
        [&](int i, bf16x8 bv8){
          if (i < 8)       cc0 = MFMA_B16(a, bv8, cc0);
          else if (i < 10) g10 = MFMA_B16(a, bv8, g10);
          else             g20 = MFMA_B16(a, bv8, g20);
          if (i + 1 < 8)        a = LA(OFF_HID,264, rA, (i+1)*32+gA*8);
          else if (i + 1 == 8)  a = LA(OFF_G1H,72, rA, gA*8);
          else if (i + 1 == 9)  a = LA(OFF_G1H,72, rA, 32+gA*8);
          else if (i + 1 == 10) a = LA(OFF_G2H,72, rA, gA*8);
          else if (i + 1 == 11) a = LA(OFF_G2H,72, rA, 32+gA*8);
        });
      #pragma unroll
      for (int j = 0; j < 4; ++j) {
        float ch = tanh_(cc0[j]), ga = sigm(g10[j]), gb = sigm(g20[j]);
        float mn = ga*mreg[j] + gb*ch;
        mreg[j] = mn;
        STB(OFF_FEATS,360, gA*4 + j, 224 + n*16 + rA, mn);
      }
    }
    __syncthreads();

    // ---- Phase 8: out layer1 ----
    if (w < 4) {
      int n = w;
      float bv = biasLds[B_OUTH + n*16 + rA];
      f32x4 a0v = {bv,bv,bv,bv};
      bf16x8 a = LA(OFF_FEATS,360, rA, gA*8);
      reg_loop<11>(packc, lane,
        [&](int i){ return 1180 + n*11 + i; },
        [&](int i, bf16x8 bv8){
          a0v = MFMA_B16(a, bv8, a0v);
          if (i + 1 < 11) a = LA(OFF_FEATS,360, rA, (i+1)*32+gA*8);
        });
      #pragma unroll
      for (int j = 0; j < 4; ++j)
        STB(OFF_HID,72, gA*4 + j, n*16 + rA, fmaxf(a0v[j], 0.f));
    }
    __syncthreads();
  }

  // ---- Final out2 for t = 127 ----
  if (w == 15) {
    float bv = biasLds[B_OUT2];
    f32x4 oa0 = {bv,bv,bv,bv};
    bf16x8 as[2], bs[2];
    #pragma unroll
    for (int s = 0; s < 2; ++s) { bs[s] = LB(1224 + s); as[s] = LA(OFF_HID,72, rA, s*32+gA*8); }
    #pragma unroll
    for (int s = 0; s < 2; ++s) oa0 = MFMA_B16(as[s], bs[s], oa0);
    if (rA == 0) {
      #pragma unroll
      for (int j = 0; j < 4; ++j)
        __builtin_nontemporal_store(oa0[j], &out[(size_t)(n0 + gA*4 + j)*T_STEPS + 127]);
    }
  }
}

extern "C" void kernel_launch(void* const* d_in, const int* in_sizes, int n_in,
                              void* d_out, int out_size, void* d_ws, size_t ws_size,
                              hipStream_t stream) {
  (void)in_sizes; (void)n_in; (void)out_size; (void)ws_size;
  PP P;
  for (int i = 0; i < 35; ++i) P.p[i] = (const float*)d_in[i];
  unsigned short* pack = (unsigned short*)d_ws;
  float* bias = (float*)((char*)d_ws + PACK_BYTES);
  unsigned short* xp = (unsigned short*)((char*)d_ws + PACK_BYTES + 16384);

  hipLaunchKernelGGL(pack_kernel, dim3(320), dim3(256), 0, stream, P, pack, bias);
  hipLaunchKernelGGL(xproj_kernel, dim3(2048), dim3(1024), 0, stream,
                     P.p[0], P.p[1], P.p[2], pack, xp);
  hipLaunchKernelGGL(fused_kernel, dim3(128), dim3(1024), 0, stream,
                     pack, bias, xp, (float*)d_out);
}